// Round 3
// baseline (355.819 us; speedup 1.0000x reference)
//
#include <hip/hip_runtime.h>

typedef unsigned short u16;
typedef unsigned int u32;
typedef __attribute__((ext_vector_type(4))) float f32x4;
typedef __attribute__((ext_vector_type(8))) short bf16x8;
typedef __attribute__((ext_vector_type(4))) unsigned short us4;

#define B_ 4
#define S_ 2048
#define D_ 1024
#define H_ 8
#define DH_ 128
#define MROWS (B_ * S_)   // 8192
#define LOG2E 1.4426950408889634f

__device__ __forceinline__ u16 f2bf(float f) {
  unsigned u = __float_as_uint(f);
  u += 0x7fffu + ((u >> 16) & 1u);   // round-to-nearest-even
  return (u16)(u >> 16);
}

__device__ __forceinline__ u32 cvt_pk_bf16(float lo, float hi) {
  u32 r;
  asm("v_cvt_pk_bf16_f32 %0, %1, %2" : "=v"(r) : "v"(lo), "v"(hi));
  return r;
}

__device__ __forceinline__ void gload_lds16(const void* g, void* l) {
  __builtin_amdgcn_global_load_lds(
      (const __attribute__((address_space(1))) void*)g,
      (__attribute__((address_space(3))) void*)l, 16, 0, 0);
}

// ---------------- cast f32 -> bf16, vectorized x4 ----------------
__global__ void cast_bf16(const float* __restrict__ src, u16* __restrict__ dst, int n4) {
  int i = blockIdx.x * blockDim.x + threadIdx.x;
  int st = gridDim.x * blockDim.x;
  for (; i < n4; i += st) {
    float4 v = reinterpret_cast<const float4*>(src)[i];
    us4 o = { f2bf(v.x), f2bf(v.y), f2bf(v.z), f2bf(v.w) };
    reinterpret_cast<us4*>(dst)[i] = o;
  }
}

// ---------------- fused QKV projection GEMM ----------------
// z=0: Qo = qb@Wq^T, row-major, PRE-SCALED by 1/32 (= 1/sqrt(D), exact pow2)
// z=1: Ko row-major; z=2: Vt transposed per-batch: Vt[(b*1024+col)*2048 + s]
#define BM 128
#define BN 128
#define BKK 32

__global__ __launch_bounds__(256) void gemm_qkv(
    const u16* __restrict__ qb, const u16* __restrict__ kb,
    const u16* __restrict__ wq, const u16* __restrict__ wk, const u16* __restrict__ wv,
    u16* __restrict__ Qo, u16* __restrict__ Ko, u16* __restrict__ Vt)
{
  const int z = blockIdx.z;
  const u16* A = (z == 0) ? qb : kb;
  const u16* W = (z == 0) ? wq : (z == 1) ? wk : wv;
  constexpr int K = D_;

  __shared__ __align__(16) u16 sA[2][BM * BKK];
  __shared__ __align__(16) u16 sB[2][BN * BKK];

  const int tid = threadIdx.x;
  const int w = tid >> 6, lane = tid & 63;
  const int brow = blockIdx.y * BM, bcol = blockIdx.x * BN;

  const int srow = w * 32 + (lane >> 2);
  const int scol = (lane & 3) * 8;
  const u16* gA = A + (brow + srow) * K + scol;
  const u16* gW = W + (bcol + srow) * K + scol;

  const int wr = (w >> 1) * 64, wc = (w & 1) * 64;
  const int fr = lane & 15, fg = lane >> 4;

  f32x4 acc[4][4] = {};

#define STAGE(bufi, k0) do { \
    gload_lds16(gA + (k0),          &sA[bufi][(w * 32) * BKK]);      \
    gload_lds16(gA + 16 * K + (k0), &sA[bufi][(w * 32 + 16) * BKK]); \
    gload_lds16(gW + (k0),          &sB[bufi][(w * 32) * BKK]);      \
    gload_lds16(gW + 16 * K + (k0), &sB[bufi][(w * 32 + 16) * BKK]); \
  } while (0)

  STAGE(0, 0);
  int cur = 0;
  for (int t = 0; t < K / BKK; ++t) {
    __syncthreads();
    if (t + 1 < K / BKK) STAGE(cur ^ 1, (t + 1) * BKK);
    bf16x8 af[4], bfr[4];
#pragma unroll
    for (int m = 0; m < 4; ++m)
      af[m] = *reinterpret_cast<const bf16x8*>(&sA[cur][(wr + m * 16 + fr) * BKK + fg * 8]);
#pragma unroll
    for (int n = 0; n < 4; ++n)
      bfr[n] = *reinterpret_cast<const bf16x8*>(&sB[cur][(wc + n * 16 + fr) * BKK + fg * 8]);
#pragma unroll
    for (int m = 0; m < 4; ++m)
#pragma unroll
      for (int n = 0; n < 4; ++n)
        acc[m][n] = __builtin_amdgcn_mfma_f32_16x16x32_bf16(af[m], bfr[n], acc[m][n], 0, 0, 0);
    cur ^= 1;
  }
#undef STAGE

  if (z < 2) {
    u16* Cp = (z == 0) ? Qo : Ko;
    const float osc = (z == 0) ? 0.03125f : 1.0f;
#pragma unroll
    for (int m = 0; m < 4; ++m)
#pragma unroll
      for (int n = 0; n < 4; ++n) {
        int row = brow + wr + m * 16 + fg * 4;
        int col = bcol + wc + n * 16 + fr;
#pragma unroll
        for (int r = 0; r < 4; ++r)
          Cp[(row + r) * D_ + col] = f2bf(acc[m][n][r] * osc);
      }
  } else {
#pragma unroll
    for (int m = 0; m < 4; ++m) {
      int grow0 = brow + wr + m * 16 + fg * 4;
      int b = grow0 >> 11, s0 = grow0 & (S_ - 1);
#pragma unroll
      for (int n = 0; n < 4; ++n) {
        int col = bcol + wc + n * 16 + fr;
        us4 v = { f2bf(acc[m][n][0]), f2bf(acc[m][n][1]),
                  f2bf(acc[m][n][2]), f2bf(acc[m][n][3]) };
        *reinterpret_cast<us4*>(&Vt[((b << 10) + col) * S_ + s0]) = v;
      }
    }
  }
}

// ---------------- flash attention + residual, in-block split-KV ----------
// 8 waves: waves 0-3 (group 0) do kv [0,1024), waves 4-7 (group 1) do
// kv [1024,2048), same 128 q-rows; merge (m,l,O) in-block via dead LDS.
// Each wave: 32 q-rows (m=2). KVBLK=32, double-buffered per group.
// LDS 80KB exactly -> 2 blocks/CU -> 16 waves/CU resident.
// Swizzles (write-side = inverse-swizzled GLOBAL source, read-side same XOR):
//   K tile [32 r][16 u16B]: phys u = u ^ (r&15)      (full 16-span, 2-way)
//   V tile [128 dh][4 u]  : phys u = u ^ ((dh>>2)&3) (+64B-row parity bit)
//   P tile [16 q][4 u]    : phys u = u ^ ((q>>1)&3)
__global__ __launch_bounds__(512) void attn_fwd(
    const u16* __restrict__ Qb, const u16* __restrict__ Kb, const u16* __restrict__ Vt,
    const float* __restrict__ query, float* __restrict__ out)
{
  __shared__ __align__(16) u16 smem[40960];   // 80KB
  // carve: K(g2): [2 buf][4096] at g2*8192 | V(g2): 16384 + g2*8192
  //        P(w,m): 32768 + (w*2+m)*512
  const int tid = threadIdx.x;
  const int w = tid >> 6, lane = tid & 63;
  const int g = lane >> 4, ql = lane & 15;
  const int wp = w & 3, g2 = w >> 2;

  // XCD-pinned decode: consecutive dispatch ids round-robin XCDs; give each
  // XCD 4 whole (h,b) pairs so K/V working set (4MB) = one L2.
  const int p = blockIdx.x;
  const int hb = (p & 7) * 4 + ((p >> 3) >> 4);
  const int qi = (p >> 3) & 15;
  const int b = hb & (B_ - 1), h = hb >> 2;
  const int q0 = qi * 128 + wp * 32;
  const int kvbase = g2 * 1024;

  u16* sK = smem + g2 * 8192;
  u16* sV = smem + 16384 + g2 * 8192;
  u16* sP = smem + 32768 + (w * 2) * 512;

  // Q frags (pre-scaled by 1/32): B-operand, lane holds q = m*16+ql, dh g*8
  bf16x8 qf[2][4];
#pragma unroll
  for (int m = 0; m < 2; ++m)
#pragma unroll
    for (int kk = 0; kk < 4; ++kk)
      qf[m][kk] = *reinterpret_cast<const bf16x8*>(
          Qb + (size_t)(b * S_ + q0 + m * 16 + ql) * D_ + h * DH_ + kk * 32 + g * 8);

  // staging sources (inverse-swizzled): instr a = wp*2+j
  const u16* gK[2];
  const u16* gV[2];
#pragma unroll
  for (int j = 0; j < 2; ++j) {
    int a = wp * 2 + j;
    int rK = a * 4 + g;                           // tile row 0..31
    int uK = (lane & 15) ^ (rK & 15);
    gK[j] = Kb + (size_t)(b * S_ + kvbase + rK) * D_ + h * DH_ + uK * 8;
    int dhV = a * 16 + (lane >> 2);               // 0..127
    int uV = (lane & 3) ^ ((lane >> 4) & 3);      // = (l&3)^((dhV>>2)&3)
    gV[j] = Vt + (size_t)((b << 10) + h * DH_ + dhV) * S_ + kvbase + uV * 8;
  }

#define ASTAGE(bufi, kvt) do { \
    gload_lds16(gK[0] + (size_t)(kvt) * D_, sK + (bufi) * 4096 + (wp * 2 + 0) * 512); \
    gload_lds16(gV[0] + (kvt),              sV + (bufi) * 4096 + (wp * 2 + 0) * 512); \
    gload_lds16(gK[1] + (size_t)(kvt) * D_, sK + (bufi) * 4096 + (wp * 2 + 1) * 512); \
    gload_lds16(gV[1] + (kvt),              sV + (bufi) * 4096 + (wp * 2 + 1) * 512); \
  } while (0)

  const float NEG_INF = -__builtin_inff();
  float m_r[2] = { NEG_INF, NEG_INF };
  float l_r[2] = { 0.f, 0.f };
  f32x4 acc[2][8] = {};

  ASTAGE(0, 0);
  int cur = 0;
  for (int kvt = 0; kvt < 1024; kvt += 32) {
    __syncthreads();                              // buf[cur] staged, prev reads done
    if (kvt + 32 < 1024) ASTAGE(cur ^ 1, kvt + 32);
    const u16* kbuf = sK + cur * 4096;
    const u16* vbuf = sV + cur * 4096;

    // QK^T swapped: sc[m][t][r] = S^T[k = t*16+g*4+r][q = m*16+ql]
    f32x4 sc[2][2] = {};
#pragma unroll
    for (int t = 0; t < 2; ++t) {
      int r = t * 16 + ql;
#pragma unroll
      for (int kk = 0; kk < 4; ++kk) {
        bf16x8 kf = *reinterpret_cast<const bf16x8*>(
            kbuf + r * 128 + (((kk * 4 + g) ^ ql) << 3));
        sc[0][t] = __builtin_amdgcn_mfma_f32_16x16x32_bf16(kf, qf[0][kk], sc[0][t], 0, 0, 0);
        sc[1][t] = __builtin_amdgcn_mfma_f32_16x16x32_bf16(kf, qf[1][kk], sc[1][t], 0, 0, 0);
      }
    }

    // online softmax per m-tile (k-reduce: 7 intra-lane fmax + 2 shuffles)
#pragma unroll
    for (int m = 0; m < 2; ++m) {
      float mx = fmaxf(fmaxf(fmaxf(sc[m][0][0], sc[m][0][1]), fmaxf(sc[m][0][2], sc[m][0][3])),
                       fmaxf(fmaxf(sc[m][1][0], sc[m][1][1]), fmaxf(sc[m][1][2], sc[m][1][3])));
      mx = fmaxf(mx, __shfl_xor(mx, 16, 64));
      mx = fmaxf(mx, __shfl_xor(mx, 32, 64));
      if (!__all(mx <= m_r[m] + 8.0f)) {          // defer-max: rare
        float mn = fmaxf(m_r[m], mx);
        float al = exp2f((m_r[m] - mn) * LOG2E);
        m_r[m] = mn;
        l_r[m] *= al;
        float alb[4];
#pragma unroll
        for (int r = 0; r < 4; ++r) alb[r] = __shfl(al, (g << 2) + r, 64);
#pragma unroll
        for (int n = 0; n < 8; ++n)
#pragma unroll
          for (int r = 0; r < 4; ++r) acc[m][n][r] *= alb[r];
      }
      float ssum = 0.f;
#pragma unroll
      for (int t = 0; t < 2; ++t) {
        float p0 = exp2f((sc[m][t][0] - m_r[m]) * LOG2E);
        float p1 = exp2f((sc[m][t][1] - m_r[m]) * LOG2E);
        float p2 = exp2f((sc[m][t][2] - m_r[m]) * LOG2E);
        float p3 = exp2f((sc[m][t][3] - m_r[m]) * LOG2E);
        ssum += (p0 + p1) + (p2 + p3);
        uint2 pk = { cvt_pk_bf16(p0, p1), cvt_pk_bf16(p2, p3) };
        // k base = t*16+g*4 -> unit c = t*2+(g>>1), half (g&1)
        int pc = (t * 2 + (g >> 1)) ^ ((ql >> 1) & 3);
        *reinterpret_cast<uint2*>(&sP[m * 512 + ql * 32 + pc * 8 + (g & 1) * 4]) = pk;
      }
      ssum += __shfl_xor(ssum, 16, 64);
      ssum += __shfl_xor(ssum, 32, 64);
      l_r[m] += ssum;
    }
    asm volatile("s_waitcnt lgkmcnt(0)" ::: "memory");   // P writes visible (wave-local)

    bf16x8 pa[2];
#pragma unroll
    for (int m = 0; m < 2; ++m)
      pa[m] = *reinterpret_cast<const bf16x8*>(
          &sP[m * 512 + ql * 32 + ((g ^ ((ql >> 1) & 3)) << 3)]);

    // PV: acc[m][n] += P[m] @ V   (vf shared across m)
#pragma unroll
    for (int n = 0; n < 8; ++n) {
      int dh = n * 16 + ql;
      bf16x8 vf = *reinterpret_cast<const bf16x8*>(
          vbuf + dh * 32 + ((g ^ ((ql >> 2) & 3)) << 3));
      acc[0][n] = __builtin_amdgcn_mfma_f32_16x16x32_bf16(pa[0], vf, acc[0][n], 0, 0, 0);
      acc[1][n] = __builtin_amdgcn_mfma_f32_16x16x32_bf16(pa[1], vf, acc[1][n], 0, 0, 0);
    }
    cur ^= 1;
  }
#undef ASTAGE

  // ---- merge the two KV-halves (group1 -> LDS, group0 combines+writes) ----
  __syncthreads();                                 // all compute done, K/V dead
  float* accx = (float*)smem;                      // 64KB: [wp][lane][16 units f32x4]
  float* mlx = (float*)(smem + 32768);             // [(wp*2+m)*16+q][2] = {m,l}
  if (g2 == 1) {
    if (lane < 16) {
#pragma unroll
      for (int m = 0; m < 2; ++m) {
        mlx[((wp * 2 + m) * 16 + lane) * 2 + 0] = m_r[m];
        mlx[((wp * 2 + m) * 16 + lane) * 2 + 1] = l_r[m];
      }
    }
    float* basex = accx + (wp * 64 + lane) * 64;
#pragma unroll
    for (int m = 0; m < 2; ++m)
#pragma unroll
      for (int n = 0; n < 8; ++n) {
        int u = m * 8 + n, pu = u ^ ql;            // per-lane bijective layout
        *reinterpret_cast<f32x4*>(basex + pu * 4) = acc[m][n];
      }
  }
  __syncthreads();
  if (g2 == 0) {
    float* basex = accx + (wp * 64 + lane) * 64;
#pragma unroll
    for (int m = 0; m < 2; ++m) {
      float m1 = mlx[((wp * 2 + m) * 16 + ql) * 2 + 0];
      float l1 = mlx[((wp * 2 + m) * 16 + ql) * 2 + 1];
      float ms = fmaxf(m_r[m], m1);
      float f0 = exp2f((m_r[m] - ms) * LOG2E);
      float f1 = exp2f((m1 - ms) * LOG2E);
      float inv = 1.0f / (l_r[m] * f0 + l1 * f1);
      float f0i = f0 * inv, f1i = f1 * inv;
      float f0b[4], f1b[4];
#pragma unroll
      for (int r = 0; r < 4; ++r) {
        f0b[r] = __shfl(f0i, (g << 2) + r, 64);
        f1b[r] = __shfl(f1i, (g << 2) + r, 64);
      }
#pragma unroll
      for (int n = 0; n < 8; ++n) {
        int u = m * 8 + n, pu = u ^ ql;
        f32x4 a1 = *reinterpret_cast<const f32x4*>(basex + pu * 4);
#pragma unroll
        for (int r = 0; r < 4; ++r) {
          int row = b * S_ + q0 + m * 16 + (g << 2) + r;
          int col = h * DH_ + n * 16 + ql;
          int idx = row * D_ + col;
          out[idx] = acc[m][n][r] * f0b[r] + a1[r] * f1b[r] + query[idx];
        }
      }
    }
  }
}

// ---------------- batch-norm (training-style, batch stats) ----------------
__global__ void bn_partial(const float* __restrict__ x, float* __restrict__ psum,
                           float* __restrict__ psum2) {
  int c = blockIdx.x * 256 + threadIdx.x;
  int r0 = blockIdx.y * 256;
  float s = 0.f, s2 = 0.f;
  for (int r = r0; r < r0 + 256; ++r) {
    float v = x[r * D_ + c];
    s += v; s2 += v * v;
  }
  psum[blockIdx.y * D_ + c] = s;
  psum2[blockIdx.y * D_ + c] = s2;
}

__global__ void bn_finalize(const float* __restrict__ psum, const float* __restrict__ psum2,
                            const float* __restrict__ gamma, const float* __restrict__ beta,
                            float* __restrict__ scale, float* __restrict__ shift) {
  int c = blockIdx.x * 256 + threadIdx.x;
  float s = 0.f, s2 = 0.f;
  for (int i = 0; i < 32; ++i) { s += psum[i * D_ + c]; s2 += psum2[i * D_ + c]; }
  float mean = s * (1.0f / (float)MROWS);
  float var = s2 * (1.0f / (float)MROWS) - mean * mean;
  float rstd = rsqrtf(var + 1e-5f);
  float sc = gamma[c] * rstd;
  scale[c] = sc;
  shift[c] = beta[c] - mean * sc;
}

__global__ void bn_apply(float* __restrict__ x, const float* __restrict__ scale,
                         const float* __restrict__ shift) {
  int i = blockIdx.x * 256 + threadIdx.x;
  int st = gridDim.x * 256;
  const int n4 = MROWS * D_ / 4;
  for (int j = i; j < n4; j += st) {
    float4 v = reinterpret_cast<const float4*>(x)[j];
    int c = (j * 4) & (D_ - 1);
    float4 sc = *reinterpret_cast<const float4*>(&scale[c]);
    float4 sh = *reinterpret_cast<const float4*>(&shift[c]);
    v.x = v.x * sc.x + sh.x; v.y = v.y * sc.y + sh.y;
    v.z = v.z * sc.z + sh.z; v.w = v.w * sc.w + sh.w;
    reinterpret_cast<float4*>(x)[j] = v;
  }
}

extern "C" void kernel_launch(void* const* d_in, const int* in_sizes, int n_in,
                              void* d_out, int out_size, void* d_ws, size_t ws_size,
                              hipStream_t stream) {
  const float* query = (const float*)d_in[0];
  const float* keys  = (const float*)d_in[1];
  const float* Wq    = (const float*)d_in[2];
  const float* Wk    = (const float*)d_in[3];
  const float* Wv    = (const float*)d_in[4];
  const float* gamma = (const float*)d_in[5];
  const float* beta  = (const float*)d_in[6];
  float* out = (float*)d_out;

  // d_out (32MB) doubles as bf16 scratch for the two big input casts.
  u16* qb = (u16*)d_out;
  u16* kb = qb + (size_t)MROWS * D_;

  u16* ws  = (u16*)d_ws;
  u16* wqb = ws;
  u16* wkb = wqb + D_ * D_;
  u16* wvb = wkb + D_ * D_;
  u16* Qb  = wvb + D_ * D_;
  u16* Kb  = Qb + (size_t)MROWS * D_;
  u16* Vt  = Kb + (size_t)MROWS * D_;
  float* fbase = (float*)(Vt + (size_t)MROWS * D_);
  float* psum  = fbase;
  float* psum2 = psum + 32 * D_;
  float* scale = psum2 + 32 * D_;
  float* shift = scale + D_;

  cast_bf16<<<dim3(2048), dim3(256), 0, stream>>>(query, qb, MROWS * D_ / 4);
  cast_bf16<<<dim3(2048), dim3(256), 0, stream>>>(keys,  kb, MROWS * D_ / 4);
  cast_bf16<<<dim3(512),  dim3(256), 0, stream>>>(Wq, wqb, D_ * D_ / 4);
  cast_bf16<<<dim3(512),  dim3(256), 0, stream>>>(Wk, wkb, D_ * D_ / 4);
  cast_bf16<<<dim3(512),  dim3(256), 0, stream>>>(Wv, wvb, D_ * D_ / 4);

  gemm_qkv<<<dim3(D_ / BN, MROWS / BM, 3), dim3(256), 0, stream>>>(
      qb, kb, wqb, wkb, wvb, Qb, Kb, Vt);

  attn_fwd<<<dim3(512), dim3(512), 0, stream>>>(Qb, Kb, Vt, query, out);

  bn_partial<<<dim3(D_ / 256, 32), dim3(256), 0, stream>>>(out, psum, psum2);
  bn_finalize<<<dim3(D_ / 256), dim3(256), 0, stream>>>(psum, psum2, gamma, beta, scale, shift);
  bn_apply<<<dim3(2048), dim3(256), 0, stream>>>(out, scale, shift);
}

// Round 4
// 335.507 us; speedup vs baseline: 1.0605x; 1.0605x over previous
//
#include <hip/hip_runtime.h>

typedef unsigned short u16;
typedef unsigned int u32;
typedef __attribute__((ext_vector_type(4))) float f32x4;
typedef __attribute__((ext_vector_type(8))) short bf16x8;
typedef __attribute__((ext_vector_type(4))) unsigned short us4;

#define B_ 4
#define S_ 2048
#define D_ 1024
#define H_ 8
#define DH_ 128
#define MROWS (B_ * S_)   // 8192
#define LOG2E 1.4426950408889634f

__device__ __forceinline__ u16 f2bf(float f) {
  unsigned u = __float_as_uint(f);
  u += 0x7fffu + ((u >> 16) & 1u);   // round-to-nearest-even
  return (u16)(u >> 16);
}

__device__ __forceinline__ u32 cvt_pk_bf16(float lo, float hi) {
  u32 r;
  asm("v_cvt_pk_bf16_f32 %0, %1, %2" : "=v"(r) : "v"(lo), "v"(hi));
  return r;
}

__device__ __forceinline__ void gload_lds16(const void* g, void* l) {
  __builtin_amdgcn_global_load_lds(
      (const __attribute__((address_space(1))) void*)g,
      (__attribute__((address_space(3))) void*)l, 16, 0, 0);
}

// ---------------- fused cast f32 -> bf16 for all 5 inputs ----------------
#define NQ4 2097152   // MROWS*D_/4
#define NW4 262144    // D_*D_/4
__global__ void cast_all(const float* __restrict__ q, const float* __restrict__ k,
                         const float* __restrict__ wq, const float* __restrict__ wk,
                         const float* __restrict__ wv,
                         u16* __restrict__ qb, u16* __restrict__ kb,
                         u16* __restrict__ wqb, u16* __restrict__ wkb,
                         u16* __restrict__ wvb) {
  const int total = NQ4 * 2 + NW4 * 3;
  int i = blockIdx.x * blockDim.x + threadIdx.x;
  int st = gridDim.x * blockDim.x;
  for (; i < total; i += st) {
    const float* s; u16* d; int j;
    if (i < NQ4)               { s = q;  d = qb;  j = i; }
    else if (i < 2 * NQ4)      { s = k;  d = kb;  j = i - NQ4; }
    else {
      int t = i - 2 * NQ4;
      int wsel = t >> 18;      // NW4 = 1<<18
      j = t & (NW4 - 1);
      s = (wsel == 0) ? wq : (wsel == 1) ? wk : wv;
      d = (wsel == 0) ? wqb : (wsel == 1) ? wkb : wvb;
    }
    float4 v = reinterpret_cast<const float4*>(s)[j];
    us4 o = { f2bf(v.x), f2bf(v.y), f2bf(v.z), f2bf(v.w) };
    reinterpret_cast<us4*>(d)[j] = o;
  }
}

// ---------------- fused QKV projection GEMM ----------------
// z=0: Qo = qb@Wq^T, row-major, PRE-SCALED by 1/32 (= 1/sqrt(D), exact pow2)
// z=1: Ko row-major; z=2: Vt transposed per-batch: Vt[(b*1024+col)*2048 + s]
#define BM 128
#define BN 128
#define BKK 32

__global__ __launch_bounds__(256) void gemm_qkv(
    const u16* __restrict__ qb, const u16* __restrict__ kb,
    const u16* __restrict__ wq, const u16* __restrict__ wk, const u16* __restrict__ wv,
    u16* __restrict__ Qo, u16* __restrict__ Ko, u16* __restrict__ Vt)
{
  const int z = blockIdx.z;
  const u16* A = (z == 0) ? qb : kb;
  const u16* W = (z == 0) ? wq : (z == 1) ? wk : wv;
  constexpr int K = D_;

  __shared__ __align__(16) u16 sA[2][BM * BKK];
  __shared__ __align__(16) u16 sB[2][BN * BKK];

  const int tid = threadIdx.x;
  const int w = tid >> 6, lane = tid & 63;
  const int brow = blockIdx.y * BM, bcol = blockIdx.x * BN;

  const int srow = w * 32 + (lane >> 2);
  const int scol = (lane & 3) * 8;
  const u16* gA = A + (brow + srow) * K + scol;
  const u16* gW = W + (bcol + srow) * K + scol;

  const int wr = (w >> 1) * 64, wc = (w & 1) * 64;
  const int fr = lane & 15, fg = lane >> 4;

  f32x4 acc[4][4] = {};

#define STAGE(bufi, k0) do { \
    gload_lds16(gA + (k0),          &sA[bufi][(w * 32) * BKK]);      \
    gload_lds16(gA + 16 * K + (k0), &sA[bufi][(w * 32 + 16) * BKK]); \
    gload_lds16(gW + (k0),          &sB[bufi][(w * 32) * BKK]);      \
    gload_lds16(gW + 16 * K + (k0), &sB[bufi][(w * 32 + 16) * BKK]); \
  } while (0)

  STAGE(0, 0);
  int cur = 0;
  for (int t = 0; t < K / BKK; ++t) {
    __syncthreads();
    if (t + 1 < K / BKK) STAGE(cur ^ 1, (t + 1) * BKK);
    bf16x8 af[4], bfr[4];
#pragma unroll
    for (int m = 0; m < 4; ++m)
      af[m] = *reinterpret_cast<const bf16x8*>(&sA[cur][(wr + m * 16 + fr) * BKK + fg * 8]);
#pragma unroll
    for (int n = 0; n < 4; ++n)
      bfr[n] = *reinterpret_cast<const bf16x8*>(&sB[cur][(wc + n * 16 + fr) * BKK + fg * 8]);
#pragma unroll
    for (int m = 0; m < 4; ++m)
#pragma unroll
      for (int n = 0; n < 4; ++n)
        acc[m][n] = __builtin_amdgcn_mfma_f32_16x16x32_bf16(af[m], bfr[n], acc[m][n], 0, 0, 0);
    cur ^= 1;
  }
#undef STAGE

  if (z < 2) {
    u16* Cp = (z == 0) ? Qo : Ko;
    const float osc = (z == 0) ? 0.03125f : 1.0f;
#pragma unroll
    for (int m = 0; m < 4; ++m)
#pragma unroll
      for (int n = 0; n < 4; ++n) {
        int row = brow + wr + m * 16 + fg * 4;
        int col = bcol + wc + n * 16 + fr;
#pragma unroll
        for (int r = 0; r < 4; ++r)
          Cp[(row + r) * D_ + col] = f2bf(acc[m][n][r] * osc);
      }
  } else {
#pragma unroll
    for (int m = 0; m < 4; ++m) {
      int grow0 = brow + wr + m * 16 + fg * 4;
      int b = grow0 >> 11, s0 = grow0 & (S_ - 1);
#pragma unroll
      for (int n = 0; n < 4; ++n) {
        int col = bcol + wc + n * 16 + fr;
        us4 v = { f2bf(acc[m][n][0]), f2bf(acc[m][n][1]),
                  f2bf(acc[m][n][2]), f2bf(acc[m][n][3]) };
        *reinterpret_cast<us4*>(&Vt[((b << 10) + col) * S_ + s0]) = v;
      }
    }
  }
}

// ---------------- flash attention + residual (round-2 structure) ----------
// 4 waves x 32 q-rows (block = 128 q), KVBLK=64, K/V double-buffered in LDS.
// + XCD-pinned block decode (r3, FETCH 155->41MB), cvt_pk P-pack (r3),
// + s_setprio(1) around MFMA clusters (T5).
__global__ __launch_bounds__(256, 2) void attn_fwd(
    const u16* __restrict__ Qb, const u16* __restrict__ Kb, const u16* __restrict__ Vt,
    const float* __restrict__ query, float* __restrict__ out)
{
  // K tile: logical [64 r][16 c(16B)], phys byte = r*256 + (c^(r&7))*16
  // V tile: logical [128 dh][8 c(16B)], phys byte = dh*128 + (c^(dh&7))*16
  // P bounce per wave,m: logical [16 q][64 k], phys u16 = q*64 + ((k>>3)^(q&7))*8 + (k&7)
  __shared__ __align__(16) u16 sK[2][64 * 128];
  __shared__ __align__(16) u16 sV[2][128 * 64];
  __shared__ __align__(16) u16 plds[4][2][16 * 64];

  const int tid = threadIdx.x;
  const int w = tid >> 6, lane = tid & 63;
  const int g = lane >> 4, ql = lane & 15;

  // XCD-pinned decode: runtime round-robins consecutive block ids over 8 XCDs;
  // give each XCD 4 whole (h,b) pairs -> K/V working set 4MB = one L2.
  const int p = blockIdx.x;
  const int hb = (p & 7) * 4 + ((p >> 3) >> 4);
  const int qi = (p >> 3) & 15;
  const int b = hb & (B_ - 1), h = hb >> 2;
  const int q0 = qi * 128 + w * 32;

  // Q fragments (pre-scaled by 1/32): B-operand, lane holds q = m*16+ql, dh g*8
  bf16x8 qf[2][4];
#pragma unroll
  for (int m = 0; m < 2; ++m)
#pragma unroll
    for (int kk = 0; kk < 4; ++kk)
      qf[m][kk] = *reinterpret_cast<const bf16x8*>(
          Qb + (size_t)(b * S_ + q0 + m * 16 + ql) * D_ + h * DH_ + kk * 32 + g * 8);

  // staging source addrs (inverse-swizzled): wave w stages instrs a = w*4+j
  const u16* gK[4];
  const u16* gV[4];
#pragma unroll
  for (int j = 0; j < 4; ++j) {
    int a = w * 4 + j;
    int rK = a * 4 + g;                       // tile row
    int cK = (lane & 15) ^ (rK & 7);          // logical 16B chunk
    gK[j] = Kb + (size_t)(b * S_ + rK) * D_ + h * DH_ + cK * 8;
    int dhV = a * 8 + (lane >> 3);
    int cV = (lane & 7) ^ (lane >> 3);
    gV[j] = Vt + (size_t)((b << 10) + h * DH_ + dhV) * S_ + cV * 8;
  }

#define ASTAGE(bufi, kv) do { \
    _Pragma("unroll") \
    for (int j = 0; j < 4; ++j) { \
      gload_lds16(gK[j] + (size_t)(kv) * D_, &sK[bufi][(w * 4 + j) * 512]); \
      gload_lds16(gV[j] + (kv),              &sV[bufi][(w * 4 + j) * 512]); \
    } \
  } while (0)

  const float NEG_INF = -__builtin_inff();
  float m_r[2] = { NEG_INF, NEG_INF };
  float l_r[2] = { 0.f, 0.f };
  f32x4 acc[2][8] = {};
  const int sbase = ((lane >> 4) << 2);       // shfl src base for q = g*4+r

  ASTAGE(0, 0);
  int cur = 0;
  for (int kv = 0; kv < S_; kv += 64) {
    __syncthreads();                           // drains vmcnt: buf[cur] ready
    if (kv + 64 < S_) ASTAGE(cur ^ 1, kv + 64);

    // QK^T swapped: sc[m][t][r] = S^T[k = t*16+g*4+r][q = m*16+ql]
    f32x4 sc[2][4] = {};
    __builtin_amdgcn_s_setprio(1);
#pragma unroll
    for (int t = 0; t < 4; ++t) {
      int r = t * 16 + ql;
#pragma unroll
      for (int kk = 0; kk < 4; ++kk) {
        bf16x8 kf = *reinterpret_cast<const bf16x8*>(
            &sK[cur][r * 128 + (((kk * 4 + g) ^ (ql & 7)) << 3)]);
        sc[0][t] = __builtin_amdgcn_mfma_f32_16x16x32_bf16(kf, qf[0][kk], sc[0][t], 0, 0, 0);
        sc[1][t] = __builtin_amdgcn_mfma_f32_16x16x32_bf16(kf, qf[1][kk], sc[1][t], 0, 0, 0);
      }
    }
    __builtin_amdgcn_s_setprio(0);

    // online softmax per m-tile
#pragma unroll
    for (int m = 0; m < 2; ++m) {
      float mx = sc[m][0][0];
#pragma unroll
      for (int t = 0; t < 4; ++t)
#pragma unroll
        for (int r = 0; r < 4; ++r)
          mx = fmaxf(mx, sc[m][t][r]);
      mx = fmaxf(mx, __shfl_xor(mx, 16, 64));
      mx = fmaxf(mx, __shfl_xor(mx, 32, 64));
      if (!__all(mx <= m_r[m] + 8.0f)) {       // defer-max: rare
        float mn = fmaxf(m_r[m], mx);
        float al = exp2f((m_r[m] - mn) * LOG2E);
        m_r[m] = mn;
        l_r[m] *= al;
        float alb[4];
#pragma unroll
        for (int r = 0; r < 4; ++r) alb[r] = __shfl(al, sbase + r, 64);
#pragma unroll
        for (int n = 0; n < 8; ++n)
#pragma unroll
          for (int r = 0; r < 4; ++r) acc[m][n][r] *= alb[r];
      }
      float ssum = 0.f;
      u16* pw = &plds[w][m][0];
#pragma unroll
      for (int t = 0; t < 4; ++t) {
        float p0 = exp2f((sc[m][t][0] - m_r[m]) * LOG2E);
        float p1 = exp2f((sc[m][t][1] - m_r[m]) * LOG2E);
        float p2 = exp2f((sc[m][t][2] - m_r[m]) * LOG2E);
        float p3 = exp2f((sc[m][t][3] - m_r[m]) * LOG2E);
        ssum += (p0 + p1) + (p2 + p3);
        uint2 pk = { cvt_pk_bf16(p0, p1), cvt_pk_bf16(p2, p3) };
        // k base = t*16+g*4 -> chunk c = t*2+(g>>1), in-chunk (g&1)*4
        *reinterpret_cast<uint2*>(
            &pw[ql * 64 + (((t * 2 + (g >> 1)) ^ (ql & 7)) << 3) + ((g & 1) << 2)]) = pk;
      }
      ssum += __shfl_xor(ssum, 16, 64);
      ssum += __shfl_xor(ssum, 32, 64);
      l_r[m] += ssum;
    }
    asm volatile("s_waitcnt lgkmcnt(0)" ::: "memory");   // P writes visible (wave-local)

    bf16x8 pa[2][2];
#pragma unroll
    for (int m = 0; m < 2; ++m)
#pragma unroll
      for (int kt = 0; kt < 2; ++kt)
        pa[m][kt] = *reinterpret_cast<const bf16x8*>(
            &plds[w][m][ql * 64 + (((kt * 4 + g) ^ (ql & 7)) << 3)]);
    asm volatile("s_waitcnt lgkmcnt(0)" ::: "memory");   // reads done before overwrite

    // PV: acc[m][n] += P[m] @ V   (vf shared across m)
    __builtin_amdgcn_s_setprio(1);
#pragma unroll
    for (int kt = 0; kt < 2; ++kt)
#pragma unroll
      for (int n = 0; n < 8; ++n) {
        int dh = n * 16 + ql;
        bf16x8 vf = *reinterpret_cast<const bf16x8*>(
            &sV[cur][dh * 64 + (((kt * 4 + g) ^ (ql & 7)) << 3)]);
        acc[0][n] = __builtin_amdgcn_mfma_f32_16x16x32_bf16(pa[0][kt], vf, acc[0][n], 0, 0, 0);
        acc[1][n] = __builtin_amdgcn_mfma_f32_16x16x32_bf16(pa[1][kt], vf, acc[1][n], 0, 0, 0);
      }
    __builtin_amdgcn_s_setprio(0);
    cur ^= 1;
  }
#undef ASTAGE

  // epilogue: O /= l, + residual. Stats live on lanes by q=ql; acc rows are q=g*4+r.
#pragma unroll
  for (int m = 0; m < 2; ++m) {
    float inv = 1.0f / l_r[m];
    float invb[4];
#pragma unroll
    for (int r = 0; r < 4; ++r) invb[r] = __shfl(inv, sbase + r, 64);
#pragma unroll
    for (int n = 0; n < 8; ++n)
#pragma unroll
      for (int r = 0; r < 4; ++r) {
        int row = b * S_ + q0 + m * 16 + ((lane >> 4) << 2) + r;
        int col = h * DH_ + n * 16 + ql;
        int idx = row * D_ + col;
        out[idx] = acc[m][n][r] * invb[r] + query[idx];
      }
  }
}

// ---------------- batch-norm (training-style, batch stats) ----------------
__global__ void bn_partial(const float* __restrict__ x, float* __restrict__ psum,
                           float* __restrict__ psum2) {
  int c = blockIdx.x * 256 + threadIdx.x;
  int r0 = blockIdx.y * 256;
  float s = 0.f, s2 = 0.f;
  for (int r = r0; r < r0 + 256; ++r) {
    float v = x[r * D_ + c];
    s += v; s2 += v * v;
  }
  psum[blockIdx.y * D_ + c] = s;
  psum2[blockIdx.y * D_ + c] = s2;
}

// finalize fused into apply: each thread owns 4 cols, reduces 32 partials,
// then normalizes its 32-row stripe with float4 access.
__global__ void bn_apply(float* __restrict__ x, const float* __restrict__ psum,
                         const float* __restrict__ psum2,
                         const float* __restrict__ gamma, const float* __restrict__ beta) {
  const int c4 = threadIdx.x * 4;              // 256 threads -> all 1024 cols
  float4 s = {0.f, 0.f, 0.f, 0.f}, s2 = {0.f, 0.f, 0.f, 0.f};
  for (int i = 0; i < 32; ++i) {
    float4 a = *reinterpret_cast<const float4*>(&psum[i * D_ + c4]);
    float4 b = *reinterpret_cast<const float4*>(&psum2[i * D_ + c4]);
    s.x += a.x; s.y += a.y; s.z += a.z; s.w += a.w;
    s2.x += b.x; s2.y += b.y; s2.z += b.z; s2.w += b.w;
  }
  const float4 gm = *reinterpret_cast<const float4*>(&gamma[c4]);
  const float4 bt = *reinterpret_cast<const float4*>(&beta[c4]);
  const float rn = 1.0f / (float)MROWS;
  float4 sc, sh;
  {
    float mean = s.x * rn, var = s2.x * rn - mean * mean;
    sc.x = gm.x * rsqrtf(var + 1e-5f); sh.x = bt.x - mean * sc.x;
    mean = s.y * rn; var = s2.y * rn - mean * mean;
    sc.y = gm.y * rsqrtf(var + 1e-5f); sh.y = bt.y - mean * sc.y;
    mean = s.z * rn; var = s2.z * rn - mean * mean;
    sc.z = gm.z * rsqrtf(var + 1e-5f); sh.z = bt.z - mean * sc.z;
    mean = s.w * rn; var = s2.w * rn - mean * mean;
    sc.w = gm.w * rsqrtf(var + 1e-5f); sh.w = bt.w - mean * sc.w;
  }
  const int r0 = blockIdx.x * 32;              // 256 blocks x 32 rows
  for (int r = r0; r < r0 + 32; ++r) {
    float4 v = *reinterpret_cast<const float4*>(&x[r * D_ + c4]);
    v.x = v.x * sc.x + sh.x; v.y = v.y * sc.y + sh.y;
    v.z = v.z * sc.z + sh.z; v.w = v.w * sc.w + sh.w;
    *reinterpret_cast<float4*>(&x[r * D_ + c4]) = v;
  }
}

extern "C" void kernel_launch(void* const* d_in, const int* in_sizes, int n_in,
                              void* d_out, int out_size, void* d_ws, size_t ws_size,
                              hipStream_t stream) {
  const float* query = (const float*)d_in[0];
  const float* keys  = (const float*)d_in[1];
  const float* Wq    = (const float*)d_in[2];
  const float* Wk    = (const float*)d_in[3];
  const float* Wv    = (const float*)d_in[4];
  const float* gamma = (const float*)d_in[5];
  const float* beta  = (const float*)d_in[6];
  float* out = (float*)d_out;

  // d_out (32MB) doubles as bf16 scratch for the two big input casts.
  u16* qb = (u16*)d_out;
  u16* kb = qb + (size_t)MROWS * D_;

  u16* ws  = (u16*)d_ws;
  u16* wqb = ws;
  u16* wkb = wqb + D_ * D_;
  u16* wvb = wkb + D_ * D_;
  u16* Qb  = wvb + D_ * D_;
  u16* Kb  = Qb + (size_t)MROWS * D_;
  u16* Vt  = Kb + (size_t)MROWS * D_;
  float* fbase = (float*)(Vt + (size_t)MROWS * D_);
  float* psum  = fbase;
  float* psum2 = psum + 32 * D_;

  cast_all<<<dim3(2048), dim3(256), 0, stream>>>(query, keys, Wq, Wk, Wv,
                                                 qb, kb, wqb, wkb, wvb);

  gemm_qkv<<<dim3(D_ / BN, MROWS / BM, 3), dim3(256), 0, stream>>>(
      qb, kb, wqb, wkb, wvb, Qb, Kb, Vt);

  attn_fwd<<<dim3(512), dim3(256), 0, stream>>>(Qb, Kb, Vt, query, out);

  bn_partial<<<dim3(D_ / 256, 32), dim3(256), 0, stream>>>(out, psum, psum2);
  bn_apply<<<dim3(256), dim3(256), 0, stream>>>(out, psum, psum2, gamma, beta);
}

// Round 5
// 322.851 us; speedup vs baseline: 1.1021x; 1.0392x over previous
//
#include <hip/hip_runtime.h>

typedef unsigned short u16;
typedef unsigned int u32;
typedef __attribute__((ext_vector_type(4))) float f32x4;
typedef __attribute__((ext_vector_type(8))) short bf16x8;
typedef __attribute__((ext_vector_type(4))) unsigned short us4;

#define B_ 4
#define S_ 2048
#define D_ 1024
#define H_ 8
#define DH_ 128
#define MROWS (B_ * S_)   // 8192
#define LOG2E 1.4426950408889634f

__device__ __forceinline__ u16 f2bf(float f) {
  unsigned u = __float_as_uint(f);
  u += 0x7fffu + ((u >> 16) & 1u);   // round-to-nearest-even
  return (u16)(u >> 16);
}

__device__ __forceinline__ u32 cvt_pk_bf16(float lo, float hi) {
  u32 r;
  asm("v_cvt_pk_bf16_f32 %0, %1, %2" : "=v"(r) : "v"(lo), "v"(hi));
  return r;
}

__device__ __forceinline__ void gload_lds16(const void* g, void* l) {
  __builtin_amdgcn_global_load_lds(
      (const __attribute__((address_space(1))) void*)g,
      (__attribute__((address_space(3))) void*)l, 16, 0, 0);
}

// ---------------- fused cast f32 -> bf16 for all 5 inputs ----------------
#define NQ4 2097152   // MROWS*D_/4
#define NW4 262144    // D_*D_/4
__global__ void cast_all(const float* __restrict__ q, const float* __restrict__ k,
                         const float* __restrict__ wq, const float* __restrict__ wk,
                         const float* __restrict__ wv,
                         u16* __restrict__ qb, u16* __restrict__ kb,
                         u16* __restrict__ wqb, u16* __restrict__ wkb,
                         u16* __restrict__ wvb) {
  const int total = NQ4 * 2 + NW4 * 3;
  int i = blockIdx.x * blockDim.x + threadIdx.x;
  int st = gridDim.x * blockDim.x;
  for (; i < total; i += st) {
    const float* s; u16* d; int j;
    if (i < NQ4)               { s = q;  d = qb;  j = i; }
    else if (i < 2 * NQ4)      { s = k;  d = kb;  j = i - NQ4; }
    else {
      int t = i - 2 * NQ4;
      int wsel = t >> 18;      // NW4 = 1<<18
      j = t & (NW4 - 1);
      s = (wsel == 0) ? wq : (wsel == 1) ? wk : wv;
      d = (wsel == 0) ? wqb : (wsel == 1) ? wkb : wvb;
    }
    float4 v = reinterpret_cast<const float4*>(s)[j];
    us4 o = { f2bf(v.x), f2bf(v.y), f2bf(v.z), f2bf(v.w) };
    reinterpret_cast<us4*>(d)[j] = o;
  }
}

// ---------------- fused QKV projection GEMM (counted-vmcnt, 3-buffer) -----
// C[row][col] = sum_k A[row][k]*W[col][k].  Tile 128x256, BK=32, 8 waves
// (wave tile 64x64).  Triple-buffered LDS; iter t: stage tile t+2, compute
// tile t, end with s_waitcnt vmcnt(3) (own 3 loads of t+2 in flight) + raw
// s_barrier => tile t+1 proven staged.  vmcnt never 0 in the main loop.
// z=0: Qo (pre-scaled 1/32); z=1: Ko; z=2: Vt[(b*1024+col)*2048 + s].
#define GBM 128
#define GBN 256
#define GBK 32

__global__ __launch_bounds__(512) void gemm_qkv(
    const u16* __restrict__ qb, const u16* __restrict__ kb,
    const u16* __restrict__ wq, const u16* __restrict__ wk, const u16* __restrict__ wv,
    u16* __restrict__ Qo, u16* __restrict__ Ko, u16* __restrict__ Vt)
{
  const int z = blockIdx.z;
  const u16* A = (z == 0) ? qb : kb;
  const u16* W = (z == 0) ? wq : (z == 1) ? wk : wv;

  // LDS tiles: [rows][4 chunks of 16B per 32-k row], physical chunk
  // pc = ch ^ ((row>>1)&3)  (uniform 8/bank floor on b128 reads)
  __shared__ __align__(16) u16 sA[3][GBM * GBK];   // 3 x 8KB
  __shared__ __align__(16) u16 sB[3][GBN * GBK];   // 3 x 16KB

  const int tid = threadIdx.x;
  const int w = tid >> 6, lane = tid & 63;
  const int fr = lane & 15, fg = lane >> 4;
  const int brow = blockIdx.y * GBM, bcol = blockIdx.x * GBN;
  const int wr = (w >> 2) * 64, wc = (w & 3) * 64;

  // staging sources (inverse-swizzled). Per wave: 1 A-instr + 2 B-instr.
  // instr covers 16 rows x 4 chunks; lane l -> row_ofs l>>2, pc l&3,
  // logical chunk ch = pc ^ ((row>>1)&3).
  const int rA = w * 16 + (lane >> 2);
  const int chA = (lane & 3) ^ ((rA >> 1) & 3);
  const u16* gA = A + (size_t)(brow + rA) * D_ + chA * 8;
  const int rB0 = (2 * w) * 16 + (lane >> 2);
  const int chB0 = (lane & 3) ^ ((rB0 >> 1) & 3);
  const u16* gB0 = W + (size_t)(bcol + rB0) * D_ + chB0 * 8;
  const int rB1 = (2 * w + 1) * 16 + (lane >> 2);
  const int chB1 = (lane & 3) ^ ((rB1 >> 1) & 3);
  const u16* gB1 = W + (size_t)(bcol + rB1) * D_ + chB1 * 8;

#define GSTAGE(bufi, kt) do { \
    gload_lds16(gA  + (kt) * GBK, &sA[bufi][w * 512]); \
    gload_lds16(gB0 + (kt) * GBK, &sB[bufi][(2 * w) * 512]); \
    gload_lds16(gB1 + (kt) * GBK, &sB[bufi][(2 * w + 1) * 512]); \
  } while (0)

  // ds_read offsets (u16 units): row*32 + swizzled-chunk*8
  int aoff[4], boff[4];
#pragma unroll
  for (int m = 0; m < 4; ++m) {
    int ra = wr + m * 16 + fr;
    aoff[m] = ra * 32 + ((fg ^ ((ra >> 1) & 3)) << 3);
  }
#pragma unroll
  for (int n = 0; n < 4; ++n) {
    int rb = wc + n * 16 + fr;
    boff[n] = rb * 32 + ((fg ^ ((rb >> 1) & 3)) << 3);
  }

  f32x4 acc[4][4] = {};

  GSTAGE(0, 0);
  GSTAGE(1, 1);
  asm volatile("s_waitcnt vmcnt(3)" ::: "memory");   // own tile-0 loads done
  __builtin_amdgcn_s_barrier();                      // => tile 0 staged by all

  int cur = 0, stg = 2;
  for (int t = 0; t < 32; ++t) {
    if (t < 30) GSTAGE(stg, t + 2);
    const u16* a_ = sA[cur];
    const u16* b_ = sB[cur];
    bf16x8 af[4], bfr[4];
#pragma unroll
    for (int m = 0; m < 4; ++m)
      af[m] = *reinterpret_cast<const bf16x8*>(a_ + aoff[m]);
#pragma unroll
    for (int n = 0; n < 4; ++n)
      bfr[n] = *reinterpret_cast<const bf16x8*>(b_ + boff[n]);
    __builtin_amdgcn_s_setprio(1);
#pragma unroll
    for (int m = 0; m < 4; ++m)
#pragma unroll
      for (int n = 0; n < 4; ++n)
        acc[m][n] = __builtin_amdgcn_mfma_f32_16x16x32_bf16(af[m], bfr[n], acc[m][n], 0, 0, 0);
    __builtin_amdgcn_s_setprio(0);
    if (t < 30) asm volatile("s_waitcnt vmcnt(3)" ::: "memory");  // t+1 landed
    else        asm volatile("s_waitcnt vmcnt(0)" ::: "memory");  // tail drain
    __builtin_amdgcn_s_barrier();
    cur = (cur == 2) ? 0 : cur + 1;
    stg = (stg == 2) ? 0 : stg + 1;
  }
#undef GSTAGE

  if (z < 2) {
    u16* Cp = (z == 0) ? Qo : Ko;
    const float osc = (z == 0) ? 0.03125f : 1.0f;   // fold 1/sqrt(D) into Q
#pragma unroll
    for (int m = 0; m < 4; ++m)
#pragma unroll
      for (int n = 0; n < 4; ++n) {
        int row = brow + wr + m * 16 + fg * 4;
        int col = bcol + wc + n * 16 + fr;
#pragma unroll
        for (int r = 0; r < 4; ++r)
          Cp[(size_t)(row + r) * D_ + col] = f2bf(acc[m][n][r] * osc);
      }
  } else {
#pragma unroll
    for (int m = 0; m < 4; ++m) {
      int grow0 = brow + wr + m * 16 + fg * 4;
      int b = grow0 >> 11, s0 = grow0 & (S_ - 1);
#pragma unroll
      for (int n = 0; n < 4; ++n) {
        int col = bcol + wc + n * 16 + fr;
        us4 v = { f2bf(acc[m][n][0]), f2bf(acc[m][n][1]),
                  f2bf(acc[m][n][2]), f2bf(acc[m][n][3]) };
        *reinterpret_cast<us4*>(&Vt[(size_t)((b << 10) + col) * S_ + s0]) = v;
      }
    }
  }
}

// ---------------- flash attention + residual (round-4, unchanged) ---------
__global__ __launch_bounds__(256, 2) void attn_fwd(
    const u16* __restrict__ Qb, const u16* __restrict__ Kb, const u16* __restrict__ Vt,
    const float* __restrict__ query, float* __restrict__ out)
{
  __shared__ __align__(16) u16 sK[2][64 * 128];
  __shared__ __align__(16) u16 sV[2][128 * 64];
  __shared__ __align__(16) u16 plds[4][2][16 * 64];

  const int tid = threadIdx.x;
  const int w = tid >> 6, lane = tid & 63;
  const int g = lane >> 4, ql = lane & 15;

  const int p = blockIdx.x;
  const int hb = (p & 7) * 4 + ((p >> 3) >> 4);
  const int qi = (p >> 3) & 15;
  const int b = hb & (B_ - 1), h = hb >> 2;
  const int q0 = qi * 128 + w * 32;

  bf16x8 qf[2][4];
#pragma unroll
  for (int m = 0; m < 2; ++m)
#pragma unroll
    for (int kk = 0; kk < 4; ++kk)
      qf[m][kk] = *reinterpret_cast<const bf16x8*>(
          Qb + (size_t)(b * S_ + q0 + m * 16 + ql) * D_ + h * DH_ + kk * 32 + g * 8);

  const u16* gK[4];
  const u16* gV[4];
#pragma unroll
  for (int j = 0; j < 4; ++j) {
    int a = w * 4 + j;
    int rK = a * 4 + g;
    int cK = (lane & 15) ^ (rK & 7);
    gK[j] = Kb + (size_t)(b * S_ + rK) * D_ + h * DH_ + cK * 8;
    int dhV = a * 8 + (lane >> 3);
    int cV = (lane & 7) ^ (lane >> 3);
    gV[j] = Vt + (size_t)((b << 10) + h * DH_ + dhV) * S_ + cV * 8;
  }

#define ASTAGE(bufi, kv) do { \
    _Pragma("unroll") \
    for (int j = 0; j < 4; ++j) { \
      gload_lds16(gK[j] + (size_t)(kv) * D_, &sK[bufi][(w * 4 + j) * 512]); \
      gload_lds16(gV[j] + (kv),              &sV[bufi][(w * 4 + j) * 512]); \
    } \
  } while (0)

  const float NEG_INF = -__builtin_inff();
  float m_r[2] = { NEG_INF, NEG_INF };
  float l_r[2] = { 0.f, 0.f };
  f32x4 acc[2][8] = {};
  const int sbase = ((lane >> 4) << 2);

  ASTAGE(0, 0);
  int cur = 0;
  for (int kv = 0; kv < S_; kv += 64) {
    __syncthreads();
    if (kv + 64 < S_) ASTAGE(cur ^ 1, kv + 64);

    f32x4 sc[2][4] = {};
    __builtin_amdgcn_s_setprio(1);
#pragma unroll
    for (int t = 0; t < 4; ++t) {
      int r = t * 16 + ql;
#pragma unroll
      for (int kk = 0; kk < 4; ++kk) {
        bf16x8 kf = *reinterpret_cast<const bf16x8*>(
            &sK[cur][r * 128 + (((kk * 4 + g) ^ (ql & 7)) << 3)]);
        sc[0][t] = __builtin_amdgcn_mfma_f32_16x16x32_bf16(kf, qf[0][kk], sc[0][t], 0, 0, 0);
        sc[1][t] = __builtin_amdgcn_mfma_f32_16x16x32_bf16(kf, qf[1][kk], sc[1][t], 0, 0, 0);
      }
    }
    __builtin_amdgcn_s_setprio(0);

#pragma unroll
    for (int m = 0; m < 2; ++m) {
      float mx = sc[m][0][0];
#pragma unroll
      for (int t = 0; t < 4; ++t)
#pragma unroll
        for (int r = 0; r < 4; ++r)
          mx = fmaxf(mx, sc[m][t][r]);
      mx = fmaxf(mx, __shfl_xor(mx, 16, 64));
      mx = fmaxf(mx, __shfl_xor(mx, 32, 64));
      if (!__all(mx <= m_r[m] + 8.0f)) {
        float mn = fmaxf(m_r[m], mx);
        float al = exp2f((m_r[m] - mn) * LOG2E);
        m_r[m] = mn;
        l_r[m] *= al;
        float alb[4];
#pragma unroll
        for (int r = 0; r < 4; ++r) alb[r] = __shfl(al, sbase + r, 64);
#pragma unroll
        for (int n = 0; n < 8; ++n)
#pragma unroll
          for (int r = 0; r < 4; ++r) acc[m][n][r] *= alb[r];
      }
      float ssum = 0.f;
      u16* pw = &plds[w][m][0];
#pragma unroll
      for (int t = 0; t < 4; ++t) {
        float p0 = exp2f((sc[m][t][0] - m_r[m]) * LOG2E);
        float p1 = exp2f((sc[m][t][1] - m_r[m]) * LOG2E);
        float p2 = exp2f((sc[m][t][2] - m_r[m]) * LOG2E);
        float p3 = exp2f((sc[m][t][3] - m_r[m]) * LOG2E);
        ssum += (p0 + p1) + (p2 + p3);
        uint2 pk = { cvt_pk_bf16(p0, p1), cvt_pk_bf16(p2, p3) };
        *reinterpret_cast<uint2*>(
            &pw[ql * 64 + (((t * 2 + (g >> 1)) ^ (ql & 7)) << 3) + ((g & 1) << 2)]) = pk;
      }
      ssum += __shfl_xor(ssum, 16, 64);
      ssum += __shfl_xor(ssum, 32, 64);
      l_r[m] += ssum;
    }
    asm volatile("s_waitcnt lgkmcnt(0)" ::: "memory");

    bf16x8 pa[2][2];
#pragma unroll
    for (int m = 0; m < 2; ++m)
#pragma unroll
      for (int kt = 0; kt < 2; ++kt)
        pa[m][kt] = *reinterpret_cast<const bf16x8*>(
            &plds[w][m][ql * 64 + (((kt * 4 + g) ^ (ql & 7)) << 3)]);
    asm volatile("s_waitcnt lgkmcnt(0)" ::: "memory");

    __builtin_amdgcn_s_setprio(1);
#pragma unroll
    for (int kt = 0; kt < 2; ++kt)
#pragma unroll
      for (int n = 0; n < 8; ++n) {
        int dh = n * 16 + ql;
        bf16x8 vf = *reinterpret_cast<const bf16x8*>(
            &sV[cur][dh * 64 + (((kt * 4 + g) ^ (ql & 7)) << 3)]);
        acc[0][n] = __builtin_amdgcn_mfma_f32_16x16x32_bf16(pa[0][kt], vf, acc[0][n], 0, 0, 0);
        acc[1][n] = __builtin_amdgcn_mfma_f32_16x16x32_bf16(pa[1][kt], vf, acc[1][n], 0, 0, 0);
      }
    __builtin_amdgcn_s_setprio(0);
    cur ^= 1;
  }
#undef ASTAGE

#pragma unroll
  for (int m = 0; m < 2; ++m) {
    float inv = 1.0f / l_r[m];
    float invb[4];
#pragma unroll
    for (int r = 0; r < 4; ++r) invb[r] = __shfl(inv, sbase + r, 64);
#pragma unroll
    for (int n = 0; n < 8; ++n)
#pragma unroll
      for (int r = 0; r < 4; ++r) {
        int row = b * S_ + q0 + m * 16 + ((lane >> 4) << 2) + r;
        int col = h * DH_ + n * 16 + ql;
        int idx = row * D_ + col;
        out[idx] = acc[m][n][r] * invb[r] + query[idx];
      }
  }
}

// ---------------- batch-norm (training-style, batch stats) ----------------
__global__ void bn_partial(const float* __restrict__ x, float* __restrict__ psum,
                           float* __restrict__ psum2) {
  int c = blockIdx.x * 256 + threadIdx.x;
  int r0 = blockIdx.y * 256;
  float s = 0.f, s2 = 0.f;
  for (int r = r0; r < r0 + 256; ++r) {
    float v = x[r * D_ + c];
    s += v; s2 += v * v;
  }
  psum[blockIdx.y * D_ + c] = s;
  psum2[blockIdx.y * D_ + c] = s2;
}

__global__ void bn_apply(float* __restrict__ x, const float* __restrict__ psum,
                         const float* __restrict__ psum2,
                         const float* __restrict__ gamma, const float* __restrict__ beta) {
  const int c4 = threadIdx.x * 4;
  float4 s = {0.f, 0.f, 0.f, 0.f}, s2 = {0.f, 0.f, 0.f, 0.f};
  for (int i = 0; i < 32; ++i) {
    float4 a = *reinterpret_cast<const float4*>(&psum[i * D_ + c4]);
    float4 b = *reinterpret_cast<const float4*>(&psum2[i * D_ + c4]);
    s.x += a.x; s.y += a.y; s.z += a.z; s.w += a.w;
    s2.x += b.x; s2.y += b.y; s2.z += b.z; s2.w += b.w;
  }
  const float4 gm = *reinterpret_cast<const float4*>(&gamma[c4]);
  const float4 bt = *reinterpret_cast<const float4*>(&beta[c4]);
  const float rn = 1.0f / (float)MROWS;
  float4 sc, sh;
  {
    float mean = s.x * rn, var = s2.x * rn - mean * mean;
    sc.x = gm.x * rsqrtf(var + 1e-5f); sh.x = bt.x - mean * sc.x;
    mean = s.y * rn; var = s2.y * rn - mean * mean;
    sc.y = gm.y * rsqrtf(var + 1e-5f); sh.y = bt.y - mean * sc.y;
    mean = s.z * rn; var = s2.z * rn - mean * mean;
    sc.z = gm.z * rsqrtf(var + 1e-5f); sh.z = bt.z - mean * sc.z;
    mean = s.w * rn; var = s2.w * rn - mean * mean;
    sc.w = gm.w * rsqrtf(var + 1e-5f); sh.w = bt.w - mean * sc.w;
  }
  const int r0 = blockIdx.x * 32;
  for (int r = r0; r < r0 + 32; ++r) {
    float4 v = *reinterpret_cast<const float4*>(&x[r * D_ + c4]);
    v.x = v.x * sc.x + sh.x; v.y = v.y * sc.y + sh.y;
    v.z = v.z * sc.z + sh.z; v.w = v.w * sc.w + sh.w;
    *reinterpret_cast<float4*>(&x[r * D_ + c4]) = v;
  }
}

extern "C" void kernel_launch(void* const* d_in, const int* in_sizes, int n_in,
                              void* d_out, int out_size, void* d_ws, size_t ws_size,
                              hipStream_t stream) {
  const float* query = (const float*)d_in[0];
  const float* keys  = (const float*)d_in[1];
  const float* Wq    = (const float*)d_in[2];
  const float* Wk    = (const float*)d_in[3];
  const float* Wv    = (const float*)d_in[4];
  const float* gamma = (const float*)d_in[5];
  const float* beta  = (const float*)d_in[6];
  float* out = (float*)d_out;

  u16* qb = (u16*)d_out;
  u16* kb = qb + (size_t)MROWS * D_;

  u16* ws  = (u16*)d_ws;
  u16* wqb = ws;
  u16* wkb = wqb + D_ * D_;
  u16* wvb = wkb + D_ * D_;
  u16* Qb  = wvb + D_ * D_;
  u16* Kb  = Qb + (size_t)MROWS * D_;
  u16* Vt  = Kb + (size_t)MROWS * D_;
  float* fbase = (float*)(Vt + (size_t)MROWS * D_);
  float* psum  = fbase;
  float* psum2 = psum + 32 * D_;

  cast_all<<<dim3(2048), dim3(256), 0, stream>>>(query, keys, Wq, Wk, Wv,
                                                 qb, kb, wqb, wkb, wvb);

  gemm_qkv<<<dim3(D_ / GBN, MROWS / GBM, 3), dim3(512), 0, stream>>>(
      qb, kb, wqb, wkb, wvb, Qb, Kb, Vt);

  attn_fwd<<<dim3(512), dim3(256), 0, stream>>>(Qb, Kb, Vt, query, out);

  bn_partial<<<dim3(D_ / 256, 32), dim3(256), 0, stream>>>(out, psum, psum2);
  bn_apply<<<dim3(256), dim3(256), 0, stream>>>(out, psum, psum2, gamma, beta);
}